// Round 8
// baseline (568.111 us; speedup 1.0000x reference)
//
#include <hip/hip_runtime.h>
#include <hip/hip_bf16.h>
#include <hip/hip_cooperative_groups.h>
namespace cg = cooperative_groups;

// Problem constants (fixed instance)
#define T_TOK 2048
#define K_DIM 2048
#define I_DIM 1024
#define NE    8
#define TOPK  2
#define GS    64

#define NSLOT  (T_TOK * TOPK)      // 4096 routed slots
#define TOTROW (NSLOT + T_TOK)     // + shared-expert rows = 6144
#define MAXITEM 55                 // max (expert, m-tile) work items

typedef __attribute__((ext_vector_type(8))) short short8;   // 8 bf16 (MFMA A/B frag)
typedef __attribute__((ext_vector_type(4))) float f32x4;    // MFMA C/D frag

// ---- workspace layout (bytes) ----
#define WS_XB   ((size_t)65536)                        // ushort xb[2048][2048]
#define WS_ACT  (WS_XB  + (size_t)2048 * 2048 * 2)     // ushort act[TOTROW][1024]
#define WS_Y    (WS_ACT + (size_t)TOTROW * 1024 * 2)   // ushort y[TOTROW][2048]
#define WS_WGU  (WS_Y   + (size_t)TOTROW * 2048 * 2)   // ushort wgu_t[9][2048][2048]
#define WS_WD   (WS_WGU + (size_t)9 * 2048 * 2048 * 2) // ushort wd_t[9][2048][1024]
// total ~159.5 MB

// Stage work counts
#define GU_ITEMS   4608            // 9 experts x 16 kw x 32 n  (gate_up dequant)
#define PREP_ITEMS 2048
#define S0_ITEMS   (GU_ITEMS + PREP_ITEMS + 1)
#define GEMM1_ITEMS (16 * MAXITEM)             // 880
#define DQD_ITEMS   2304                       // 9 x 8 kw x 32 n (down dequant)
#define S1_ITEMS   (GEMM1_ITEMS + DQD_ITEMS)
#define S2_ITEMS   (16 * MAXITEM)              // 880
#define S3_ITEMS   2048

// k-permutation sigma = {0,2,4,6,1,3,5,7} within each 8-block on BOTH operands
// (dot-product invariant); falls out of the byte-parallel nibble decode.

__device__ __forceinline__ unsigned pack2(float a, float b) {
    __hip_bfloat162 h = __float22bfloat162_rn(make_float2(a, b)); // x=low
    return *reinterpret_cast<unsigned*>(&h);
}

__device__ __forceinline__ unsigned scale2(unsigned p, float s) {
    float f0 = __uint_as_float(p << 16) * s;
    float f1 = __uint_as_float(p & 0xFFFF0000u) * s;
    return pack2(f0, f1);
}

__device__ __forceinline__ float bf2f(ushort h) {
    return __uint_as_float((unsigned)h << 16);
}

__device__ __forceinline__ void dq_word(unsigned w, float s, unsigned o[4]) {
    unsigned lo  = w & 0x0F0F0F0Fu;
    unsigned hi  = (w >> 4) & 0x0F0F0F0Fu;
    unsigned mlo = lo & 0x07070707u, mhi = hi & 0x07070707u;
    unsigned Hlo = __builtin_amdgcn_perm(0x40404040u, 0x3F3F3F00u, mlo);
    unsigned Hhi = __builtin_amdgcn_perm(0x40404040u, 0x3F3F3F00u, mhi);
    unsigned Llo = __builtin_amdgcn_perm(0xC0804000u, 0xC0800000u, mlo);
    unsigned Lhi = __builtin_amdgcn_perm(0xC0804000u, 0xC0800000u, mhi);
    Hlo |= (lo & 0x08080808u) << 4;
    Hhi |= (hi & 0x08080808u) << 4;
    unsigned e01 = __builtin_amdgcn_perm(Hlo, Llo, 0x05010400u);
    unsigned e23 = __builtin_amdgcn_perm(Hlo, Llo, 0x07030602u);
    unsigned o01 = __builtin_amdgcn_perm(Hhi, Lhi, 0x05010400u);
    unsigned o23 = __builtin_amdgcn_perm(Hhi, Lhi, 0x07030602u);
    o[0] = scale2(e01, s); o[1] = scale2(e23, s);
    o[2] = scale2(o01, s); o[3] = scale2(o23, s);
}

// Dequant 4 consecutive k-words (64 weights) for one column n; coalesced reads.
__device__ __forceinline__ void dq4(const int* __restrict__ wp, const float* __restrict__ sc,
                                    ushort* __restrict__ op, int KW, int kb, int nb, int tid) {
    const int N = 2048;
    int n   = nb * 64 + (tid & 63);
    int kwt = kb * 16 + (tid >> 6) * 4;     // offsets {0,4,8,12}: single scale group each
    float s = sc[(size_t)(kwt >> 3) * N + n];
    ushort* dst = op + (size_t)n * (KW * 8) + kwt * 8;
    #pragma unroll
    for (int j = 0; j < 4; j++) {
        unsigned w = (unsigned)wp[(size_t)(kwt + j) * N + n];
        unsigned o[4]; dq_word(w, s, o);
        *(int4*)(dst + j * 8) = make_int4(o[0], o[1], o[2], o[3]);
    }
}

__device__ __forceinline__ void gld16(const void* g, void* l) {
    __builtin_amdgcn_global_load_lds(
        (const __attribute__((address_space(1))) unsigned*)g,
        (__attribute__((address_space(3))) unsigned*)l, 16, 0, 0);
}

__global__ __launch_bounds__(256, 3) void k_moe(
        const float* __restrict__ x,
        const int* __restrict__ gup, const float* __restrict__ gus,
        const int* __restrict__ sup, const float* __restrict__ sus,
        const int* __restrict__ dwp, const float* __restrict__ dsc,
        const int* __restrict__ sdp, const float* __restrict__ sds,
        const int* __restrict__ eids, const float* __restrict__ prb,
        float* __restrict__ out, char* __restrict__ wsb) {
    int*    gcnt    = (int*)(wsb + 0);
    int*    gbase   = (int*)(wsb + 64);
    int*    tileCnt = (int*)(wsb + 128);
    int*    tileE   = (int*)(wsb + 192);
    int*    tileM   = (int*)(wsb + 448);
    int*    tok     = (int*)(wsb + 1024);
    int*    inv     = (int*)(wsb + 25600);
    ushort* xb      = (ushort*)(wsb + WS_XB);
    ushort* act     = (ushort*)(wsb + WS_ACT);
    ushort* y       = (ushort*)(wsb + WS_Y);
    ushort* wgu_t   = (ushort*)(wsb + WS_WGU);
    ushort* wd_t    = (ushort*)(wsb + WS_WD);

    __shared__ __align__(16) ushort xs[128 * 64];
    __shared__ __align__(16) ushort bs[128 * 64];
    __shared__ int ltok[128];
    __shared__ int lcnt[NE], lbase[NE], lcur[NE];

    cg::grid_group grid = cg::this_grid();
    int tid = threadIdx.x;
    int nb  = gridDim.x;
    int lane = tid & 63, wv = tid >> 6;
    int lid = lane & 15, quad = lane >> 4;
    int wr = wv >> 1, wc = wv & 1;
    int l8 = lane >> 3, l7 = lane & 7;
    int chunk = (l7 ^ l8) * 8;

    // ================= S0: gate_up dequant + x prep + routing =================
    for (int it = blockIdx.x; it < S0_ITEMS; it += nb) {
        if (it < GU_ITEMS) {
            int e = it >> 9, rem = it & 511;
            int kb = rem & 15, nbl = rem >> 4;
            const int* wp; const float* sc;
            if (e < NE) { wp = gup + (size_t)e * 256 * 2048; sc = gus + (size_t)e * 32 * 2048; }
            else        { wp = sup; sc = sus; }
            dq4(wp, sc, wgu_t + (size_t)e * 2048 * 2048, 256, kb, nbl, tid);
        } else if (it < GU_ITEMS + PREP_ITEMS) {
            int idx = (it - GU_ITEMS) * 256 + tid;
            const float4* p = (const float4*)(x + (size_t)idx * 8);
            float4 f0 = p[0], f1 = p[1];
            unsigned u0 = pack2(f0.x, f0.z);
            unsigned u1 = pack2(f1.x, f1.z);
            unsigned u2 = pack2(f0.y, f0.w);
            unsigned u3 = pack2(f1.y, f1.w);
            *(int4*)(xb + (size_t)idx * 8) = make_int4(u0, u1, u2, u3);
        } else {
            if (tid < NE) lcnt[tid] = 0;
            __syncthreads();
            for (int i = tid; i < NSLOT; i += 256)
                atomicAdd(&lcnt[eids[i]], 1);
            __syncthreads();
            if (tid == 0) {
                int acc = 0;
                for (int e = 0; e < NE; e++) { lbase[e] = acc; acc += lcnt[e]; }
            }
            __syncthreads();
            if (tid < NE) lcur[tid] = lbase[tid];
            __syncthreads();
            for (int i = tid; i < NSLOT; i += 256) {
                int e = eids[i];
                int pos = atomicAdd(&lcur[e], 1);
                tok[pos] = i >> 1;
                inv[i] = pos;
            }
            for (int t = tid; t < T_TOK; t += 256)
                tok[NSLOT + t] = t;
            if (tid < NE) { gcnt[tid] = lcnt[tid]; gbase[tid] = lbase[tid]; }
            if (tid == 0) {
                gcnt[NE] = T_TOK; gbase[NE] = NSLOT;
                int nt = 0;
                for (int e = 0; e < NE + 1; e++) {
                    int c = (e < NE) ? lcnt[e] : T_TOK;
                    for (int m = 0; m < c; m += 128) { tileE[nt] = e; tileM[nt] = m; nt++; }
                }
                *tileCnt = nt;                             // <= 55
                for (int i = nt; i < 64; i++) { tileE[i] = 0; tileM[i] = 0; }
            }
        }
    }
    __threadfence();
    grid.sync();

    // ================= S1: gate_up GEMM tiles + down dequant =================
    int nTiles = *tileCnt;
    for (int it = blockIdx.x; it < S1_ITEMS; it += nb) {
        if (it < GEMM1_ITEMS) {
            int item = it >> 4;
            if (item >= nTiles) continue;
            int e = tileE[item], m0 = tileM[item];
            int cnt = gcnt[e], base = gbase[e];
            int n0 = (it & 15) * 64;
            const ushort* wt = wgu_t + (size_t)e * 2048 * K_DIM;

            if (tid < 128) ltok[tid] = (m0 + tid < cnt) ? tok[base + m0 + tid] : 0;
            __syncthreads();

            const ushort* aSrc[4]; const ushort* bSrc[4];
            #pragma unroll
            for (int s4 = 0; s4 < 4; s4++) {
                int rA = wv * 32 + s4 * 8 + l8;
                aSrc[s4] = xb + (size_t)ltok[rA] * K_DIM + chunk;
                int h = rA >> 6, j = rA & 63;
                int col = (j < 32) ? (n0 + h * 32 + j) : (I_DIM + n0 + h * 32 + (j - 32));
                bSrc[s4] = wt + (size_t)col * K_DIM + chunk;
            }

            f32x4 acc[4][4] = {};
            for (int k0 = 0; k0 < K_DIM; k0 += 64) {
                #pragma unroll
                for (int s4 = 0; s4 < 4; s4++) {
                    gld16(aSrc[s4] + k0, &xs[(wv * 4 + s4) * 512]);
                    gld16(bSrc[s4] + k0, &bs[(wv * 4 + s4) * 512]);
                }
                __syncthreads();
                #pragma unroll
                for (int ks = 0; ks < 2; ks++) {
                    int slot = ((ks * 4 + quad) ^ l7) * 8;
                    short8 a[4], b[4];
                    #pragma unroll
                    for (int mt = 0; mt < 4; mt++)
                        a[mt] = *(const short8*)&xs[(wr * 64 + mt * 16 + lid) * 64 + slot];
                    #pragma unroll
                    for (int nt = 0; nt < 4; nt++)
                        b[nt] = *(const short8*)&bs[(wc * 64 + nt * 16 + lid) * 64 + slot];
                    #pragma unroll
                    for (int mt = 0; mt < 4; mt++)
                        #pragma unroll
                        for (int nt = 0; nt < 4; nt++)
                            acc[mt][nt] = __builtin_amdgcn_mfma_f32_16x16x32_bf16(
                                a[mt], b[nt], acc[mt][nt], 0, 0, 0);
                }
                __syncthreads();
            }

            int c7 = lid & 7;
            int delta = ((c7 >> 1) + ((c7 & 1) << 2)) - c7;   // sigma^-1 on stored I index
            #pragma unroll
            for (int mt = 0; mt < 4; mt++) {
                #pragma unroll
                for (int i = 0; i < 4; i++) {
                    int row = wr * 64 + mt * 16 + quad * 4 + i;
                    if (m0 + row < cnt) {
                        size_t p = (size_t)(base + m0 + row);
                        #pragma unroll
                        for (int nt = 0; nt < 2; nt++) {
                            float g = acc[mt][nt][i], u = acc[mt][nt + 2][i];
                            float vv = g / (1.f + __expf(-g)) * u;
                            int ncol = n0 + wc * 32 + nt * 16 + lid;
                            __hip_bfloat16 hb = __float2bfloat16(vv);
                            act[p * I_DIM + ncol + delta] = *reinterpret_cast<ushort*>(&hb);
                        }
                    }
                }
            }
        } else {                                  // down dequant (KW=128)
            int id2 = it - GEMM1_ITEMS;
            int e = id2 >> 8, rem = id2 & 255;
            int kb = rem & 7, nbl = rem >> 3;
            const int* wp; const float* sc;
            if (e < NE) { wp = dwp + (size_t)e * 128 * 2048; sc = dsc + (size_t)e * 16 * 2048; }
            else        { wp = sdp; sc = sds; }
            dq4(wp, sc, wd_t + (size_t)e * 2048 * 1024, 128, kb, nbl, tid);
        }
    }
    __threadfence();
    grid.sync();

    // ================= S2: down GEMM tiles =================
    for (int it = blockIdx.x; it < S2_ITEMS; it += nb) {
        int item = it >> 4;
        if (item >= nTiles) continue;
        int e = tileE[item], m0 = tileM[item];
        int cnt = gcnt[e], base = gbase[e];
        int n0 = (it & 15) * 128;
        const ushort* wt = wd_t + (size_t)e * 2048 * I_DIM;

        const ushort* aSrc[4]; const ushort* bSrc[4];
        #pragma unroll
        for (int s4 = 0; s4 < 4; s4++) {
            int rA = wv * 32 + s4 * 8 + l8;
            int rr = m0 + rA; if (rr >= cnt) rr = cnt - 1;
            aSrc[s4] = act + (size_t)(base + rr) * I_DIM + chunk;
            bSrc[s4] = wt + (size_t)(n0 + rA) * I_DIM + chunk;
        }

        f32x4 acc[4][4] = {};
        for (int i0 = 0; i0 < I_DIM; i0 += 64) {
            #pragma unroll
            for (int s4 = 0; s4 < 4; s4++) {
                gld16(aSrc[s4] + i0, &xs[(wv * 4 + s4) * 512]);
                gld16(bSrc[s4] + i0, &bs[(wv * 4 + s4) * 512]);
            }
            __syncthreads();
            #pragma unroll
            for (int ks = 0; ks < 2; ks++) {
                int slot = ((ks * 4 + quad) ^ l7) * 8;
                short8 a[4], b[4];
                #pragma unroll
                for (int mt = 0; mt < 4; mt++)
                    a[mt] = *(const short8*)&xs[(wr * 64 + mt * 16 + lid) * 64 + slot];
                #pragma unroll
                for (int nt = 0; nt < 4; nt++)
                    b[nt] = *(const short8*)&bs[(wc * 64 + nt * 16 + lid) * 64 + slot];
                #pragma unroll
                for (int mt = 0; mt < 4; mt++)
                    #pragma unroll
                    for (int nt = 0; nt < 4; nt++)
                        acc[mt][nt] = __builtin_amdgcn_mfma_f32_16x16x32_bf16(
                            a[mt], b[nt], acc[mt][nt], 0, 0, 0);
            }
            __syncthreads();
        }

        #pragma unroll
        for (int mt = 0; mt < 4; mt++) {
            #pragma unroll
            for (int i = 0; i < 4; i++) {
                int row = wr * 64 + mt * 16 + quad * 4 + i;
                if (m0 + row < cnt) {
                    ushort* yrow = y + (size_t)(base + m0 + row) * 2048 + n0 + wc * 64 + lid;
                    #pragma unroll
                    for (int nt = 0; nt < 4; nt++) {
                        __hip_bfloat16 hb = __float2bfloat16(acc[mt][nt][i]);
                        yrow[nt * 16] = *reinterpret_cast<ushort*>(&hb);
                    }
                }
            }
        }
    }
    __threadfence();
    grid.sync();

    // ================= S3: combine =================
    for (int it = blockIdx.x; it < S3_ITEMS; it += nb) {
        int idx = it * 256 + tid;
        int t = idx >> 8;
        int c = (idx & 255) * 8;
        int p0 = inv[2 * t], p1 = inv[2 * t + 1];
        float w0 = prb[2 * t], w1 = prb[2 * t + 1];
        int4 a = *(const int4*)(y + (size_t)p0 * 2048 + c);
        int4 b = *(const int4*)(y + (size_t)p1 * 2048 + c);
        int4 s = *(const int4*)(y + (size_t)(NSLOT + t) * 2048 + c);
        const ushort* au = (const ushort*)&a;
        const ushort* bu = (const ushort*)&b;
        const ushort* su = (const ushort*)&s;
        float o[8];
        #pragma unroll
        for (int j = 0; j < 8; j++)
            o[j] = w0 * bf2f(au[j]) + w1 * bf2f(bu[j]) + bf2f(su[j]);
        *(float4*)(out + (size_t)t * 2048 + c)     = *(float4*)&o[0];
        *(float4*)(out + (size_t)t * 2048 + c + 4) = *(float4*)&o[4];
    }
}

extern "C" void kernel_launch(void* const* d_in, const int* in_sizes, int n_in,
                              void* d_out, int out_size, void* d_ws, size_t ws_size,
                              hipStream_t stream) {
    const float* x    = (const float*)d_in[0];
    const int*   gup  = (const int*)d_in[1];
    const float* gus  = (const float*)d_in[2];
    const int*   dwp  = (const int*)d_in[3];
    const float* dsc  = (const float*)d_in[4];
    const int*   sup  = (const int*)d_in[5];
    const float* sus  = (const float*)d_in[6];
    const int*   sdp  = (const int*)d_in[7];
    const float* sds  = (const float*)d_in[8];
    const int*   eids = (const int*)d_in[9];
    const float* prb  = (const float*)d_in[10];
    float* out = (float*)d_out;
    char*  wsb = (char*)d_ws;

    int maxb = 0;
    hipOccupancyMaxActiveBlocksPerMultiprocessor(&maxb, k_moe, 256, 0);
    if (maxb < 1) maxb = 1;
    if (maxb > 4) maxb = 4;
    int grid = 256 * maxb;

    void* args[] = { (void*)&x, (void*)&gup, (void*)&gus, (void*)&sup, (void*)&sus,
                     (void*)&dwp, (void*)&dsc, (void*)&sdp, (void*)&sds,
                     (void*)&eids, (void*)&prb, (void*)&out, (void*)&wsb };
    hipLaunchCooperativeKernel((const void*)k_moe, dim3(grid), dim3(256),
                               args, 0, stream);
}

// Round 9
// 241.201 us; speedup vs baseline: 2.3553x; 2.3553x over previous
//
#include <hip/hip_runtime.h>
#include <hip/hip_bf16.h>

// Problem constants (fixed instance)
#define T_TOK 2048
#define K_DIM 2048
#define I_DIM 1024
#define NE    8
#define TOPK  2
#define GS    64

#define NSLOT  (T_TOK * TOPK)      // 4096 routed slots
#define TOTROW (NSLOT + T_TOK)     // + shared-expert rows = 6144
#define MAXITEM 32                 // max (expert, 256-row m-tile) work items
#define DQD_Y   72                 // extra blockIdx.y slots in gateup for down-dq (72*8*4=2304)

typedef __attribute__((ext_vector_type(8))) short short8;   // 8 bf16 (MFMA A/B frag)
typedef __attribute__((ext_vector_type(4))) float f32x4;    // MFMA C/D frag

// ---- workspace layout (bytes) ----
// 0: gcnt[16] | 64: gbase[16] | 128: tileCnt | 192: tileE[64] | 448: tileM[64]
// 1024: tok[6144] | 25600: inv[4096]
#define WS_XB   ((size_t)65536)                        // ushort xb[2048][2048]
#define WS_ACT  (WS_XB  + (size_t)2048 * 2048 * 2)     // ushort act[TOTROW][1024]
#define WS_Y    (WS_ACT + (size_t)TOTROW * 1024 * 2)   // ushort y[TOTROW][2048]
#define WS_WGU  (WS_Y   + (size_t)TOTROW * 2048 * 2)   // ushort wgu_t[9][2048][2048]
#define WS_WD   (WS_WGU + (size_t)9 * 2048 * 2048 * 2) // ushort wd_t[9][2048][1024]
// total ~159.5 MB

// k-permutation sigma = {0,2,4,6,1,3,5,7} within each 8-block on BOTH operands
// (dot-product invariant); falls out of the byte-parallel nibble decode.

__device__ __forceinline__ unsigned pack2(float a, float b) {
    __hip_bfloat162 h = __float22bfloat162_rn(make_float2(a, b)); // x=low
    return *reinterpret_cast<unsigned*>(&h);
}

__device__ __forceinline__ unsigned scale2(unsigned p, float s) {
    float f0 = __uint_as_float(p << 16) * s;
    float f1 = __uint_as_float(p & 0xFFFF0000u) * s;
    return pack2(f0, f1);
}

__device__ __forceinline__ float bf2f(ushort h) {
    return __uint_as_float((unsigned)h << 16);
}

__device__ __forceinline__ void dq_word(unsigned w, float s, unsigned o[4]) {
    unsigned lo  = w & 0x0F0F0F0Fu;
    unsigned hi  = (w >> 4) & 0x0F0F0F0Fu;
    unsigned mlo = lo & 0x07070707u, mhi = hi & 0x07070707u;
    unsigned Hlo = __builtin_amdgcn_perm(0x40404040u, 0x3F3F3F00u, mlo);
    unsigned Hhi = __builtin_amdgcn_perm(0x40404040u, 0x3F3F3F00u, mhi);
    unsigned Llo = __builtin_amdgcn_perm(0xC0804000u, 0xC0800000u, mlo);
    unsigned Lhi = __builtin_amdgcn_perm(0xC0804000u, 0xC0800000u, mhi);
    Hlo |= (lo & 0x08080808u) << 4;
    Hhi |= (hi & 0x08080808u) << 4;
    unsigned e01 = __builtin_amdgcn_perm(Hlo, Llo, 0x05010400u);
    unsigned e23 = __builtin_amdgcn_perm(Hlo, Llo, 0x07030602u);
    unsigned o01 = __builtin_amdgcn_perm(Hhi, Lhi, 0x05010400u);
    unsigned o23 = __builtin_amdgcn_perm(Hhi, Lhi, 0x07030602u);
    o[0] = scale2(e01, s); o[1] = scale2(e23, s);
    o[2] = scale2(o01, s); o[3] = scale2(o23, s);
}

// Dequant 4 consecutive k-words (64 weights) for one column n; coalesced reads.
// tid must be in [0, 256).
__device__ __forceinline__ void dq4(const int* __restrict__ wp, const float* __restrict__ sc,
                                    ushort* __restrict__ op, int KW, int kb, int nb, int tid) {
    const int N = 2048;
    int n   = nb * 64 + (tid & 63);
    int kwt = kb * 16 + (tid >> 6) * 4;     // offsets {0,4,8,12}: single scale group each
    float s = sc[(size_t)(kwt >> 3) * N + n];
    ushort* dst = op + (size_t)n * (KW * 8) + kwt * 8;
    #pragma unroll
    for (int j = 0; j < 4; j++) {
        unsigned w = (unsigned)wp[(size_t)(kwt + j) * N + n];
        unsigned o[4]; dq_word(w, s, o);
        *(int4*)(dst + j * 8) = make_int4(o[0], o[1], o[2], o[3]);
    }
}

__device__ __forceinline__ void gld16(const void* g, void* l) {
    __builtin_amdgcn_global_load_lds(
        (const __attribute__((address_space(1))) unsigned*)g,
        (__attribute__((address_space(3))) unsigned*)l, 16, 0, 0);
}

// ---- front end: gate_up dequant + x prep + routing (down dequant rides in gateup)
#define GU_BLK  (9 * 512)        // 9 experts x (16 kw-tiles x 32 n-tiles)
#define PREP_BLK 2048
#define FRONT_GRID (GU_BLK + PREP_BLK + 1)

__global__ __launch_bounds__(256) void k_front(
        const float* __restrict__ x, ushort* __restrict__ xb,
        const int* __restrict__ gup, const float* __restrict__ gus,
        const int* __restrict__ sup, const float* __restrict__ sus,
        ushort* __restrict__ wgu_t,
        const int* __restrict__ eids, const float* __restrict__ probs,
        int* __restrict__ gcnt, int* __restrict__ gbase,
        int* __restrict__ tileCnt, int* __restrict__ tileE, int* __restrict__ tileM,
        int* __restrict__ tok, int* __restrict__ inv) {
    int id = blockIdx.x;
    int tid = threadIdx.x;

    if (id < GU_BLK) {                                // gate_up dequant (KW=256)
        int e = id >> 9, rem = id & 511;
        int kb = rem & 15, nb = rem >> 4;
        const int* wp; const float* sc;
        if (e < NE) { wp = gup + (size_t)e * 256 * 2048; sc = gus + (size_t)e * 32 * 2048; }
        else        { wp = sup; sc = sus; }
        dq4(wp, sc, wgu_t + (size_t)e * 2048 * 2048, 256, kb, nb, tid);
    } else if (id < GU_BLK + PREP_BLK) {              // x fp32 -> sigma-bf16
        int idx = (id - GU_BLK) * 256 + tid;
        const float4* p = (const float4*)(x + (size_t)idx * 8);
        float4 f0 = p[0], f1 = p[1];
        unsigned u0 = pack2(f0.x, f0.z);
        unsigned u1 = pack2(f1.x, f1.z);
        unsigned u2 = pack2(f0.y, f0.w);
        unsigned u3 = pack2(f1.y, f1.w);
        *(int4*)(xb + (size_t)idx * 8) = make_int4(u0, u1, u2, u3);
    } else {                                           // routing + work-list
        __shared__ int lcnt[NE], lbase[NE], lcur[NE];
        if (tid < NE) lcnt[tid] = 0;
        __syncthreads();
        for (int i = tid; i < NSLOT; i += 256)
            atomicAdd(&lcnt[eids[i]], 1);
        __syncthreads();
        if (tid == 0) {
            int acc = 0;
            for (int e = 0; e < NE; e++) { lbase[e] = acc; acc += lcnt[e]; }
        }
        __syncthreads();
        if (tid < NE) lcur[tid] = lbase[tid];
        __syncthreads();
        for (int i = tid; i < NSLOT; i += 256) {
            int e = eids[i];
            int pos = atomicAdd(&lcur[e], 1);
            tok[pos] = i >> 1;
            inv[i] = pos;
        }
        for (int t = tid; t < T_TOK; t += 256)
            tok[NSLOT + t] = t;
        if (tid < NE) { gcnt[tid] = lcnt[tid]; gbase[tid] = lbase[tid]; }
        if (tid == 0) {
            gcnt[NE] = T_TOK; gbase[NE] = NSLOT;
            int nt = 0;
            for (int e = 0; e < NE + 1; e++) {
                int c = (e < NE) ? lcnt[e] : T_TOK;
                for (int m = 0; m < c; m += 256) { tileE[nt] = e; tileM[nt] = m; nt++; }
            }
            *tileCnt = nt;                             // <= 32
            for (int i = nt; i < 64; i++) { tileE[i] = 0; tileM[i] = 0; }
        }
    }
}

// ---- GEMM 1: act[p,n] = silu(x@Wg)*(x@Wu). 256 rows x (128 gate + 128 up) per
// block, 1024 threads = 16 waves of the verified 64x64 wave-tile / BK=64 /
// XOR-swizzle inner loop. Halves L2/L3 re-read traffic vs 128-tiles.
// blockIdx.y >= MAXITEM: down-weight dequant rides along.
__global__ __launch_bounds__(1024) void k_gemm_gateup(
        const ushort* __restrict__ xb, const ushort* __restrict__ wgu_t,
        const int* __restrict__ dwp, const float* __restrict__ dsc,
        const int* __restrict__ sdp, const float* __restrict__ sds,
        ushort* __restrict__ wd_t,
        const int* __restrict__ gcnt, const int* __restrict__ gbase,
        const int* __restrict__ tileCnt, const int* __restrict__ tileE,
        const int* __restrict__ tileM,
        const int* __restrict__ tokid, ushort* __restrict__ act) {
    int tid = threadIdx.x;
    if (blockIdx.y >= MAXITEM) {                      // down dequant (KW=128)
        int id2 = ((blockIdx.y - MAXITEM) * 8 + blockIdx.x) * 4 + (tid >> 8); // [0,2304)
        int e = id2 >> 8, rem = id2 & 255;
        int kb = rem & 7, nbl = rem >> 3;
        const int* wp; const float* sc;
        if (e < NE) { wp = dwp + (size_t)e * 128 * 2048; sc = dsc + (size_t)e * 16 * 2048; }
        else        { wp = sdp; sc = sds; }
        dq4(wp, sc, wd_t + (size_t)e * 2048 * 1024, 128, kb, nbl, tid & 255);
        return;
    }
    int item = blockIdx.y;
    if (item >= *tileCnt) return;
    int e = tileE[item], m0 = tileM[item];
    int cnt = gcnt[e], base = gbase[e];
    int n0 = blockIdx.x * 128;                         // act cols per block
    const ushort* wt = wgu_t + (size_t)e * 2048 * K_DIM;

    __shared__ __align__(16) ushort xs[256 * 64];      // 32 KB
    __shared__ __align__(16) ushort bs[256 * 64];      // 32 KB

    int lane = tid & 63, wv = tid >> 6;                // 16 waves
    int lid = lane & 15, quad = lane >> 4;
    int wr = wv >> 2, wc = wv & 3;                     // 4x4 waves of 64x64
    int l8 = lane >> 3, l7 = lane & 7;
    int chunk = (l7 ^ l8) * 8;

    // per-lane staging sources: 2 rows each for A and B (16 rows/wave)
    const ushort* aSrc[2]; const ushort* bSrc[2];
    #pragma unroll
    for (int it = 0; it < 2; it++) {
        int rA = wv * 16 + it * 8 + l8;                // rA & 7 == l8
        int t = (m0 + rA < cnt) ? tokid[base + m0 + rA] : 0;
        aSrc[it] = xb + (size_t)t * K_DIM + chunk;
        int h = rA >> 6, j = rA & 63;                  // B row -> weight col
        int col = (j < 32) ? (n0 + h * 32 + j) : (I_DIM + n0 + h * 32 + (j - 32));
        bSrc[it] = wt + (size_t)col * K_DIM + chunk;
    }

    f32x4 acc[4][4] = {};

    for (int k0 = 0; k0 < K_DIM; k0 += 64) {
        #pragma unroll
        for (int it = 0; it < 2; it++) {
            gld16(aSrc[it] + k0, &xs[(wv * 2 + it) * 512]);
            gld16(bSrc[it] + k0, &bs[(wv * 2 + it) * 512]);
        }
        __syncthreads();
        #pragma unroll
        for (int ks = 0; ks < 2; ks++) {
            int slot = ((ks * 4 + quad) ^ l7) * 8;
            short8 a[4], b[4];
            #pragma unroll
            for (int mt = 0; mt < 4; mt++)
                a[mt] = *(const short8*)&xs[(wr * 64 + mt * 16 + lid) * 64 + slot];
            #pragma unroll
            for (int nt = 0; nt < 4; nt++)
                b[nt] = *(const short8*)&bs[(wc * 64 + nt * 16 + lid) * 64 + slot];
            #pragma unroll
            for (int mt = 0; mt < 4; mt++)
                #pragma unroll
                for (int nt = 0; nt < 4; nt++)
                    acc[mt][nt] = __builtin_amdgcn_mfma_f32_16x16x32_bf16(
                        a[mt], b[nt], acc[mt][nt], 0, 0, 0);
        }
        __syncthreads();
    }

    int c7 = lid & 7;
    int delta = ((c7 >> 1) + ((c7 & 1) << 2)) - c7;   // sigma^-1 on stored I index
    #pragma unroll
    for (int mt = 0; mt < 4; mt++) {
        #pragma unroll
        for (int i = 0; i < 4; i++) {
            int row = wr * 64 + mt * 16 + quad * 4 + i;
            if (m0 + row < cnt) {
                size_t p = (size_t)(base + m0 + row);
                #pragma unroll
                for (int nt = 0; nt < 2; nt++) {
                    float g = acc[mt][nt][i], u = acc[mt][nt + 2][i];
                    float vv = g / (1.f + __expf(-g)) * u;
                    int ncol = n0 + wc * 32 + nt * 16 + lid;
                    __hip_bfloat16 hb = __float2bfloat16(vv);
                    act[p * I_DIM + ncol + delta] = *reinterpret_cast<ushort*>(&hb);
                }
            }
        }
    }
}

// ---- GEMM 2: y[p,n] = (act @ Wd)[p,n]. 256 rows x 256 cols, 1024 threads.
__global__ __launch_bounds__(1024) void k_gemm_down(
        const ushort* __restrict__ actb, const ushort* __restrict__ wd_t,
        const int* __restrict__ gcnt, const int* __restrict__ gbase,
        const int* __restrict__ tileCnt, const int* __restrict__ tileE,
        const int* __restrict__ tileM,
        ushort* __restrict__ y) {
    int item = blockIdx.y;
    if (item >= *tileCnt) return;
    int e = tileE[item], m0 = tileM[item];
    int cnt = gcnt[e], base = gbase[e];
    int n0 = blockIdx.x * 256;
    const ushort* wt = wd_t + (size_t)e * 2048 * I_DIM;

    __shared__ __align__(16) ushort xs[256 * 64];
    __shared__ __align__(16) ushort bs[256 * 64];

    int tid = threadIdx.x;
    int lane = tid & 63, wv = tid >> 6;
    int lid = lane & 15, quad = lane >> 4;
    int wr = wv >> 2, wc = wv & 3;
    int l8 = lane >> 3, l7 = lane & 7;
    int chunk = (l7 ^ l8) * 8;

    const ushort* aSrc[2]; const ushort* bSrc[2];
    #pragma unroll
    for (int it = 0; it < 2; it++) {
        int rA = wv * 16 + it * 8 + l8;
        int rr = m0 + rA; if (rr >= cnt) rr = cnt - 1;
        aSrc[it] = actb + (size_t)(base + rr) * I_DIM + chunk;
        bSrc[it] = wt + (size_t)(n0 + rA) * I_DIM + chunk;
    }

    f32x4 acc[4][4] = {};

    for (int i0 = 0; i0 < I_DIM; i0 += 64) {
        #pragma unroll
        for (int it = 0; it < 2; it++) {
            gld16(aSrc[it] + i0, &xs[(wv * 2 + it) * 512]);
            gld16(bSrc[it] + i0, &bs[(wv * 2 + it) * 512]);
        }
        __syncthreads();
        #pragma unroll
        for (int ks = 0; ks < 2; ks++) {
            int slot = ((ks * 4 + quad) ^ l7) * 8;
            short8 a[4], b[4];
            #pragma unroll
            for (int mt = 0; mt < 4; mt++)
                a[mt] = *(const short8*)&xs[(wr * 64 + mt * 16 + lid) * 64 + slot];
            #pragma unroll
            for (int nt = 0; nt < 4; nt++)
                b[nt] = *(const short8*)&bs[(wc * 64 + nt * 16 + lid) * 64 + slot];
            #pragma unroll
            for (int mt = 0; mt < 4; mt++)
                #pragma unroll
                for (int nt = 0; nt < 4; nt++)
                    acc[mt][nt] = __builtin_amdgcn_mfma_f32_16x16x32_bf16(
                        a[mt], b[nt], acc[mt][nt], 0, 0, 0);
        }
        __syncthreads();
    }

    #pragma unroll
    for (int mt = 0; mt < 4; mt++) {
        #pragma unroll
        for (int i = 0; i < 4; i++) {
            int row = wr * 64 + mt * 16 + quad * 4 + i;
            if (m0 + row < cnt) {
                ushort* yrow = y + (size_t)(base + m0 + row) * 2048 + n0 + wc * 64 + lid;
                #pragma unroll
                for (int nt = 0; nt < 4; nt++) {
                    __hip_bfloat16 hb = __float2bfloat16(acc[mt][nt][i]);
                    yrow[nt * 16] = *reinterpret_cast<ushort*>(&hb);
                }
            }
        }
    }
}

// out[t] = p0*y[inv[2t]] + p1*y[inv[2t+1]] + y[NSLOT+t]
__global__ __launch_bounds__(256) void k_combine(
        const ushort* __restrict__ y, const int* __restrict__ inv,
        const float* __restrict__ prb, float* __restrict__ out) {
    int idx = blockIdx.x * 256 + threadIdx.x;
    int t = idx >> 8;
    int c = (idx & 255) * 8;
    int p0 = inv[2 * t], p1 = inv[2 * t + 1];
    float w0 = prb[2 * t], w1 = prb[2 * t + 1];
    int4 a = *(const int4*)(y + (size_t)p0 * 2048 + c);
    int4 b = *(const int4*)(y + (size_t)p1 * 2048 + c);
    int4 s = *(const int4*)(y + (size_t)(NSLOT + t) * 2048 + c);
    const ushort* au = (const ushort*)&a;
    const ushort* bu = (const ushort*)&b;
    const ushort* su = (const ushort*)&s;
    float o[8];
    #pragma unroll
    for (int j = 0; j < 8; j++)
        o[j] = w0 * bf2f(au[j]) + w1 * bf2f(bu[j]) + bf2f(su[j]);
    *(float4*)(out + (size_t)t * 2048 + c)     = *(float4*)&o[0];
    *(float4*)(out + (size_t)t * 2048 + c + 4) = *(float4*)&o[4];
}

extern "C" void kernel_launch(void* const* d_in, const int* in_sizes, int n_in,
                              void* d_out, int out_size, void* d_ws, size_t ws_size,
                              hipStream_t stream) {
    const float* x    = (const float*)d_in[0];
    const int*   gup  = (const int*)d_in[1];
    const float* gus  = (const float*)d_in[2];
    const int*   dwp  = (const int*)d_in[3];
    const float* dsc  = (const float*)d_in[4];
    const int*   sup  = (const int*)d_in[5];
    const float* sus  = (const float*)d_in[6];
    const int*   sdp  = (const int*)d_in[7];
    const float* sds  = (const float*)d_in[8];
    const int*   eids = (const int*)d_in[9];
    const float* prb  = (const float*)d_in[10];
    float* out = (float*)d_out;

    char*   ws      = (char*)d_ws;
    int*    gcnt    = (int*)(ws + 0);
    int*    gbase   = (int*)(ws + 64);
    int*    tileCnt = (int*)(ws + 128);
    int*    tileE   = (int*)(ws + 192);
    int*    tileM   = (int*)(ws + 448);
    int*    tok     = (int*)(ws + 1024);
    int*    inv     = (int*)(ws + 25600);
    ushort* xb      = (ushort*)(ws + WS_XB);
    ushort* act     = (ushort*)(ws + WS_ACT);
    ushort* y       = (ushort*)(ws + WS_Y);
    ushort* wgu_t   = (ushort*)(ws + WS_WGU);
    ushort* wd_t    = (ushort*)(ws + WS_WD);

    k_front<<<FRONT_GRID, 256, 0, stream>>>(
        x, xb, gup, gus, sup, sus, wgu_t,
        eids, prb, gcnt, gbase, tileCnt, tileE, tileM, tok, inv);
    k_gemm_gateup<<<dim3(I_DIM / 128, MAXITEM + DQD_Y), 1024, 0, stream>>>(
        xb, wgu_t, dwp, dsc, sdp, sds, wd_t,
        gcnt, gbase, tileCnt, tileE, tileM, tok, act);
    k_gemm_down<<<dim3(K_DIM / 256, MAXITEM), 1024, 0, stream>>>(
        act, wd_t, gcnt, gbase, tileCnt, tileE, tileM, y);
    k_combine<<<(T_TOK * K_DIM / 8) / 256, 256, 0, stream>>>(y, inv, prb, out);
}